// Round 6
// baseline (366.180 us; speedup 1.0000x reference)
//
#include <hip/hip_runtime.h>
#include <cstdint>
#include <cstddef>

#define B_ 2
#define T_ 2048
#define C_ 768
#define H_ 12
#define D_ 64

typedef __attribute__((ext_vector_type(8))) short s16x8;
typedef __attribute__((ext_vector_type(4))) float fx4;

static __device__ __forceinline__ unsigned short f2bf(float f) {
  unsigned u = __builtin_bit_cast(unsigned, f);
  unsigned r = u + 0x7fffu + ((u >> 16) & 1u);
  return (unsigned short)(r >> 16);
}

static __device__ __forceinline__ void glds16(const unsigned short* g, unsigned short* l) {
  __builtin_amdgcn_global_load_lds(
      (const __attribute__((address_space(1))) void*)(g),
      (__attribute__((address_space(3))) void*)(l), 16, 0, 0);
}

// ---------------- weight transpose + cast: W[R][C] fp32 -> Wt[C][R] bf16 ----
__global__ __launch_bounds__(256) void transpose_cast(
    const float* __restrict__ W, unsigned short* __restrict__ Wt, int R, int C) {
  __shared__ float tile[32][33];
  int tx = threadIdx.x & 31;
  int ty = threadIdx.x >> 5;  // 0..7
  int c0 = blockIdx.x * 32, r0 = blockIdx.y * 32;
#pragma unroll
  for (int i = 0; i < 4; ++i)
    tile[ty + i * 8][tx] = W[(size_t)(r0 + ty + i * 8) * C + (c0 + tx)];
  __syncthreads();
#pragma unroll
  for (int i = 0; i < 4; ++i)
    Wt[(size_t)(c0 + ty + i * 8) * R + (r0 + tx)] = f2bf(tile[tx][ty + i * 8]);
}

// ---------------- layernorm fp32 -> bf16 ------------------------------------
__global__ __launch_bounds__(256) void layernorm_bf16(
    const float* __restrict__ X, const float* __restrict__ g,
    const float* __restrict__ bb, unsigned short* __restrict__ O) {
  int row = blockIdx.x, tid = threadIdx.x;
  const float* xr = X + (size_t)row * C_;
  float v0 = xr[tid], v1 = xr[tid + 256], v2 = xr[tid + 512];
  float s = v0 + v1 + v2;
  float s2 = v0 * v0 + v1 * v1 + v2 * v2;
#pragma unroll
  for (int off = 1; off < 64; off <<= 1) {
    s += __shfl_xor(s, off);
    s2 += __shfl_xor(s2, off);
  }
  __shared__ float ps[8];
  int wv = tid >> 6;
  if ((tid & 63) == 0) { ps[wv] = s; ps[wv + 4] = s2; }
  __syncthreads();
  s = ps[0] + ps[1] + ps[2] + ps[3];
  s2 = ps[4] + ps[5] + ps[6] + ps[7];
  float mu = s * (1.f / C_);
  float var = s2 * (1.f / C_) - mu * mu;
  float rstd = rsqrtf(var + 1e-5f);
  unsigned short* orow = O + (size_t)row * C_;
  orow[tid]       = f2bf((v0 - mu) * rstd * g[tid]       + bb[tid]);
  orow[tid + 256] = f2bf((v1 - mu) * rstd * g[tid + 256] + bb[tid + 256]);
  orow[tid + 512] = f2bf((v2 - mu) * rstd * g[tid + 512] + bb[tid + 512]);
}

// ---------------- double-buffered GEMM: C = A[M,K] * Bt[N,K]^T + bias -------
// 256 threads = 4 waves (2x2); glds width-16 staging; LDS double buffer.
// BK==64 uses an XOR swizzle on the 8-element column group (r4: 16-way
// conflict fix). MODE 0: QKV scatter; MODE 1: resid+bias fp32; MODE 2: gelu.
template <int BM, int BN, int BK, int MODE>
__global__ __launch_bounds__(256) void gemm_db(
    const unsigned short* __restrict__ A, const unsigned short* __restrict__ Bt,
    const float* __restrict__ bias, const float* __restrict__ resid,
    float* __restrict__ outF, unsigned short* __restrict__ outB,
    unsigned short* __restrict__ qO, unsigned short* __restrict__ kO,
    unsigned short* __restrict__ vtO, int M, int N, int K) {
  constexpr int AT = BM / 32;
  constexpr int BT = BN / 32;
  constexpr int KS = BK / 32;
  constexpr int CA = BM * BK / 2048;
  constexpr int CB = BN * BK / 2048;
  constexpr int ASZ = BM * BK, BSZ = BN * BK;
  constexpr bool SWIZ = (BK == 64);
  __shared__ __align__(16) unsigned short As[2 * ASZ];
  __shared__ __align__(16) unsigned short Bs[2 * BSZ];
  int tid = threadIdx.x;
  int wv = tid >> 6, lane = tid & 63, quad = lane >> 4, l15 = lane & 15;
  int wm = wv >> 1, wn = wv & 1;
  int m0, n0;
  if (MODE == 1) { m0 = blockIdx.x * BM; n0 = blockIdx.y * BN; }
  else           { n0 = blockIdx.x * BN; m0 = blockIdx.y * BM; }
  fx4 acc[AT][BT];
#pragma unroll
  for (int i = 0; i < AT; ++i)
#pragma unroll
    for (int j = 0; j < BT; ++j) acc[i][j] = fx4{0.f, 0.f, 0.f, 0.f};

  int nk = K / BK;
#pragma unroll
  for (int i = 0; i < CA; ++i) {
    int e = (i * 256 + tid) * 8;
    int row = e / BK, col = e & (BK - 1);
    if (SWIZ) col = (((col >> 3) ^ (row & 7)) << 3);
    glds16(&A[(size_t)(m0 + row) * K + col], &As[(i * 256 + (tid & ~63)) * 8]);
  }
#pragma unroll
  for (int i = 0; i < CB; ++i) {
    int e = (i * 256 + tid) * 8;
    int row = e / BK, col = e & (BK - 1);
    if (SWIZ) col = (((col >> 3) ^ (row & 7)) << 3);
    glds16(&Bt[(size_t)(n0 + row) * K + col], &Bs[(i * 256 + (tid & ~63)) * 8]);
  }
  for (int kt = 0; kt < nk; ++kt) {
    int cur = kt & 1;
    __syncthreads();
    if (kt + 1 < nk) {
      int kb = (kt + 1) * BK;
      int nxt = cur ^ 1;
#pragma unroll
      for (int i = 0; i < CA; ++i) {
        int e = (i * 256 + tid) * 8;
        int row = e / BK, col = e & (BK - 1);
        if (SWIZ) col = (((col >> 3) ^ (row & 7)) << 3);
        glds16(&A[(size_t)(m0 + row) * K + kb + col],
               &As[nxt * ASZ + (i * 256 + (tid & ~63)) * 8]);
      }
#pragma unroll
      for (int i = 0; i < CB; ++i) {
        int e = (i * 256 + tid) * 8;
        int row = e / BK, col = e & (BK - 1);
        if (SWIZ) col = (((col >> 3) ^ (row & 7)) << 3);
        glds16(&Bt[(size_t)(n0 + row) * K + kb + col],
               &Bs[nxt * BSZ + (i * 256 + (tid & ~63)) * 8]);
      }
    }
#pragma unroll
    for (int ks = 0; ks < KS; ++ks) {
      s16x8 af[AT], bf[BT];
#pragma unroll
      for (int mt = 0; mt < AT; ++mt) {
        int r = wm * (BM / 2) + mt * 16 + l15;
        int c = ks * 32 + quad * 8;
        if (SWIZ) c = (((c >> 3) ^ (r & 7)) << 3);
        af[mt] = *(const s16x8*)&As[cur * ASZ + r * BK + c];
      }
#pragma unroll
      for (int nt = 0; nt < BT; ++nt) {
        int r = wn * (BN / 2) + nt * 16 + l15;
        int c = ks * 32 + quad * 8;
        if (SWIZ) c = (((c >> 3) ^ (r & 7)) << 3);
        bf[nt] = *(const s16x8*)&Bs[cur * BSZ + r * BK + c];
      }
#pragma unroll
      for (int mt = 0; mt < AT; ++mt)
#pragma unroll
        for (int nt = 0; nt < BT; ++nt)
          acc[mt][nt] = __builtin_amdgcn_mfma_f32_16x16x32_bf16(af[mt], bf[nt], acc[mt][nt], 0, 0, 0);
    }
  }

#pragma unroll
  for (int mt = 0; mt < AT; ++mt)
#pragma unroll
    for (int nt = 0; nt < BT; ++nt)
#pragma unroll
      for (int r = 0; r < 4; ++r) {
        int m = m0 + wm * (BM / 2) + mt * 16 + quad * 4 + r;
        int n = n0 + wn * (BN / 2) + nt * 16 + l15;
        float v = acc[mt][nt][r] + bias[n];
        if (MODE == 0) {
          int which = n / C_;
          int within = n - which * C_;
          int hd = within >> 6, d = within & 63;
          int bbx = m >> 11, t = m & 2047;
          size_t bh = (size_t)(bbx * H_ + hd);
          unsigned short bv = f2bf(v);
          if (which == 0)      qO[(bh * T_ + t) * D_ + d] = bv;
          else if (which == 1) kO[(bh * T_ + t) * D_ + d] = bv;
          else                 vtO[(bh * D_ + d) * T_ + t] = bv;
        } else if (MODE == 1) {
          outF[(size_t)m * N + n] = resid[(size_t)m * N + n] + v;
        } else {
          float gl = 0.5f * v * (1.f + erff(v * 0.70710678118654752f));
          outB[(size_t)m * N + n] = f2bf(gl);
        }
      }
}

// ---------------- fused causal flash attention (barrier-free) ---------------
// K/V MFMA B-operand fragments are loaded DIRECTLY from global as 16B/lane
// vector loads (K natural layout, V pre-transposed [bh,d,t]) — no K/V LDS,
// no __syncthreads anywhere. Each wave is fully independent; the only LDS
// use is the per-wave P round-trip (C-layout -> A-operand layout).
__global__ __launch_bounds__(256) void attn_fused(
    const unsigned short* __restrict__ Q, const unsigned short* __restrict__ Kg,
    const unsigned short* __restrict__ Vt, unsigned short* __restrict__ Y) {
  __shared__ __align__(16) unsigned short Ps[4][16 * 72];
  int tid = threadIdx.x;
  int wv = tid >> 6, lane = tid & 63, quad = lane >> 4, l15 = lane & 15;
  // load-balance swizzle across the three 256-block dispatch waves
  int l = blockIdx.x;
  int w = l >> 8, s = l & 255;
  int g = s >> 5, i = s & 31;
  int qt, bh;
  if (w == 0)      { qt = i;              bh = g; }
  else if (w == 1) { qt = 31 - i;         bh = 8 + g; }
  else             { qt = (i + 16) & 31;  bh = 16 + g; }
  int bbx = bh / H_, hh = bh - bbx * H_;
  int q0 = qt * 64;
  size_t base = (size_t)bh * T_ * D_;
  size_t vbase = (size_t)bh * D_ * T_;
  int qrow = q0 + wv * 16 + l15;
  s16x8 qf0 = *(const s16x8*)&Q[base + (size_t)qrow * D_ + quad * 8];
  s16x8 qf1 = *(const s16x8*)&Q[base + (size_t)qrow * D_ + 32 + quad * 8];
  float lsum[4];
  fx4 oacc[4];
#pragma unroll
  for (int t = 0; t < 4; ++t) {
    lsum[t] = 0.f;
    oacc[t] = fx4{0.f, 0.f, 0.f, 0.f};
  }
  unsigned short* pw = &Ps[wv][0];
  for (int kb = 0; kb <= qt; ++kb) {
    int k0 = kb * 64;
    const unsigned short* Kt = Kg + base + (size_t)k0 * D_;
    // K fragments: B[n=key][k=dim]; 16B/lane direct global loads
    s16x8 kf0[4], kf1[4], vf0[4], vf1[4];
#pragma unroll
    for (int nt = 0; nt < 4; ++nt) {
      kf0[nt] = *(const s16x8*)&Kt[(nt * 16 + l15) * D_ + quad * 8];
      kf1[nt] = *(const s16x8*)&Kt[(nt * 16 + l15) * D_ + 32 + quad * 8];
    }
    // V fragments: B[n=dim][k=key]; issued early so vmcnt overlaps softmax
#pragma unroll
    for (int nt = 0; nt < 4; ++nt) {
      vf0[nt] = *(const s16x8*)&Vt[vbase + (size_t)(nt * 16 + l15) * T_ + k0 + quad * 8];
      vf1[nt] = *(const s16x8*)&Vt[vbase + (size_t)(nt * 16 + l15) * T_ + k0 + 32 + quad * 8];
    }
    fx4 sc[4];
#pragma unroll
    for (int nt = 0; nt < 4; ++nt) {
      sc[nt] = fx4{0.f, 0.f, 0.f, 0.f};
      sc[nt] = __builtin_amdgcn_mfma_f32_16x16x32_bf16(qf0, kf0[nt], sc[nt], 0, 0, 0);
      sc[nt] = __builtin_amdgcn_mfma_f32_16x16x32_bf16(qf1, kf1[nt], sc[nt], 0, 0, 0);
    }
    bool diag = (kb == qt);
#pragma unroll
    for (int nt = 0; nt < 4; ++nt)
#pragma unroll
      for (int r = 0; r < 4; ++r) {
        float p;
        if (diag && (k0 + nt * 16 + l15) > (q0 + wv * 16 + quad * 4 + r)) {
          p = 0.f;
        } else {
          p = __expf(sc[nt][r] * 0.125f);
        }
        lsum[r] += p;
        pw[(quad * 4 + r) * 72 + nt * 16 + l15] = f2bf(p);
      }
    // same-wave LDS round-trip (lgkmcnt only, no barrier)
    s16x8 pa0 = *(const s16x8*)&pw[l15 * 72 + quad * 8];
    s16x8 pa1 = *(const s16x8*)&pw[l15 * 72 + 32 + quad * 8];
#pragma unroll
    for (int nt = 0; nt < 4; ++nt) {
      oacc[nt] = __builtin_amdgcn_mfma_f32_16x16x32_bf16(pa0, vf0[nt], oacc[nt], 0, 0, 0);
      oacc[nt] = __builtin_amdgcn_mfma_f32_16x16x32_bf16(pa1, vf1[nt], oacc[nt], 0, 0, 0);
    }
  }
#pragma unroll
  for (int r = 0; r < 4; ++r) {
#pragma unroll
    for (int off = 1; off < 16; off <<= 1) lsum[r] += __shfl_xor(lsum[r], off);
  }
#pragma unroll
  for (int nt = 0; nt < 4; ++nt)
#pragma unroll
    for (int r = 0; r < 4; ++r) {
      float o = oacc[nt][r] / lsum[r];
      int token = bbx * T_ + q0 + wv * 16 + quad * 4 + r;
      Y[(size_t)token * C_ + hh * D_ + nt * 16 + l15] = f2bf(o);
    }
}

// ---------------- launcher --------------------------------------------------
extern "C" void kernel_launch(void* const* d_in, const int* in_sizes, int n_in,
                              void* d_out, int out_size, void* d_ws, size_t ws_size,
                              hipStream_t stream) {
  const float* x      = (const float*)d_in[0];
  const float* ln1g   = (const float*)d_in[1];
  const float* ln1b   = (const float*)d_in[2];
  const float* Wattn  = (const float*)d_in[3];
  const float* battn  = (const float*)d_in[4];
  const float* Wcproj = (const float*)d_in[5];
  const float* bcproj = (const float*)d_in[6];
  const float* ln2g   = (const float*)d_in[7];
  const float* ln2b   = (const float*)d_in[8];
  const float* Wfc    = (const float*)d_in[9];
  const float* bfc    = (const float*)d_in[10];
  const float* Wmproj = (const float*)d_in[11];
  const float* bmproj = (const float*)d_in[12];
  float* out = (float*)d_out;
  char* ws = (char*)d_ws;

  unsigned short* WattnT  = (unsigned short*)(ws + 0);          // 2304x768 bf16
  unsigned short* WcprojT = (unsigned short*)(ws + 3538944);    // 768x768
  unsigned short* WfcT    = (unsigned short*)(ws + 4718592);    // 3072x768
  unsigned short* WmprojT = (unsigned short*)(ws + 9437184);    // 768x3072
  unsigned short* hbuf    = (unsigned short*)(ws + 14155776);   // 4096x768 bf16
  unsigned short* Qb      = (unsigned short*)(ws + 20447232);   // [24,2048,64]
  unsigned short* Kb      = (unsigned short*)(ws + 26738688);   // [24,2048,64]
  unsigned short* Vtb     = (unsigned short*)(ws + 33030144);   // [24,64,2048]
  unsigned short* Yb      = (unsigned short*)(ws + 39321600);   // 4096x768 bf16
  float*          x1      = (float*)(ws + 45613056);            // 4096x768 fp32
  unsigned short* Ab      = (unsigned short*)(ws + 58195968);   // 4096x3072 bf16

  transpose_cast<<<dim3(2304 / 32, 768 / 32), 256, 0, stream>>>(Wattn, WattnT, 768, 2304);
  transpose_cast<<<dim3(768 / 32, 768 / 32), 256, 0, stream>>>(Wcproj, WcprojT, 768, 768);
  transpose_cast<<<dim3(3072 / 32, 768 / 32), 256, 0, stream>>>(Wfc, WfcT, 768, 3072);
  transpose_cast<<<dim3(768 / 32, 3072 / 32), 256, 0, stream>>>(Wmproj, WmprojT, 3072, 768);

  layernorm_bf16<<<4096, 256, 0, stream>>>(x, ln1g, ln1b, hbuf);

  gemm_db<128, 128, 32, 0><<<dim3(2304 / 128, 4096 / 128), 256, 0, stream>>>(
      hbuf, WattnT, battn, nullptr, nullptr, nullptr, Qb, Kb, Vtb, 4096, 2304, 768);

  attn_fused<<<768, 256, 0, stream>>>(Qb, Kb, Vtb, Yb);

  // cproj: x1 = x + Yb*Wc + bias  (m-tile fastest in grid.x for L2 locality)
  gemm_db<128, 64, 64, 1><<<dim3(4096 / 128, 768 / 64), 256, 0, stream>>>(
      Yb, WcprojT, bcproj, x, x1, nullptr, nullptr, nullptr, nullptr, 4096, 768, 768);

  layernorm_bf16<<<4096, 256, 0, stream>>>(x1, ln2g, ln2b, hbuf);

  gemm_db<128, 128, 32, 2><<<dim3(3072 / 128, 4096 / 128), 256, 0, stream>>>(
      hbuf, WfcT, bfc, nullptr, nullptr, Ab, nullptr, nullptr, nullptr, 4096, 3072, 768);

  // mproj: out = x1 + Ab*Wm + bias
  gemm_db<128, 64, 64, 1><<<dim3(4096 / 128, 768 / 64), 256, 0, stream>>>(
      Ab, WmprojT, bmproj, x1, out, nullptr, nullptr, nullptr, nullptr, 4096, 768, 3072);
}

// Round 7
// 272.116 us; speedup vs baseline: 1.3457x; 1.3457x over previous
//
#include <hip/hip_runtime.h>
#include <cstdint>
#include <cstddef>

#define B_ 2
#define T_ 2048
#define C_ 768
#define H_ 12
#define D_ 64

typedef __attribute__((ext_vector_type(8))) short s16x8;
typedef __attribute__((ext_vector_type(4))) float fx4;

static __device__ __forceinline__ unsigned short f2bf(float f) {
  unsigned u = __builtin_bit_cast(unsigned, f);
  unsigned r = u + 0x7fffu + ((u >> 16) & 1u);
  return (unsigned short)(r >> 16);
}
// truncating cast (for P in [0,1]; saves ~3 VALU ops vs round-to-nearest)
static __device__ __forceinline__ unsigned short f2bf_trunc(float f) {
  return (unsigned short)(__builtin_bit_cast(unsigned, f) >> 16);
}

static __device__ __forceinline__ void glds16(const unsigned short* g, unsigned short* l) {
  __builtin_amdgcn_global_load_lds(
      (const __attribute__((address_space(1))) void*)(g),
      (__attribute__((address_space(3))) void*)(l), 16, 0, 0);
}

// ---------------- weight transpose + cast: W[R][C] fp32 -> Wt[C][R] bf16 ----
__global__ __launch_bounds__(256) void transpose_cast(
    const float* __restrict__ W, unsigned short* __restrict__ Wt, int R, int C) {
  __shared__ float tile[32][33];
  int tx = threadIdx.x & 31;
  int ty = threadIdx.x >> 5;  // 0..7
  int c0 = blockIdx.x * 32, r0 = blockIdx.y * 32;
#pragma unroll
  for (int i = 0; i < 4; ++i)
    tile[ty + i * 8][tx] = W[(size_t)(r0 + ty + i * 8) * C + (c0 + tx)];
  __syncthreads();
#pragma unroll
  for (int i = 0; i < 4; ++i)
    Wt[(size_t)(c0 + ty + i * 8) * R + (r0 + tx)] = f2bf(tile[tx][ty + i * 8]);
}

// ---------------- layernorm fp32 -> bf16 ------------------------------------
__global__ __launch_bounds__(256) void layernorm_bf16(
    const float* __restrict__ X, const float* __restrict__ g,
    const float* __restrict__ bb, unsigned short* __restrict__ O) {
  int row = blockIdx.x, tid = threadIdx.x;
  const float* xr = X + (size_t)row * C_;
  float v0 = xr[tid], v1 = xr[tid + 256], v2 = xr[tid + 512];
  float s = v0 + v1 + v2;
  float s2 = v0 * v0 + v1 * v1 + v2 * v2;
#pragma unroll
  for (int off = 1; off < 64; off <<= 1) {
    s += __shfl_xor(s, off);
    s2 += __shfl_xor(s2, off);
  }
  __shared__ float ps[8];
  int wv = tid >> 6;
  if ((tid & 63) == 0) { ps[wv] = s; ps[wv + 4] = s2; }
  __syncthreads();
  s = ps[0] + ps[1] + ps[2] + ps[3];
  s2 = ps[4] + ps[5] + ps[6] + ps[7];
  float mu = s * (1.f / C_);
  float var = s2 * (1.f / C_) - mu * mu;
  float rstd = rsqrtf(var + 1e-5f);
  unsigned short* orow = O + (size_t)row * C_;
  orow[tid]       = f2bf((v0 - mu) * rstd * g[tid]       + bb[tid]);
  orow[tid + 256] = f2bf((v1 - mu) * rstd * g[tid + 256] + bb[tid + 256]);
  orow[tid + 512] = f2bf((v2 - mu) * rstd * g[tid + 512] + bb[tid + 512]);
}

// ---------------- double-buffered GEMM: C = A[M,K] * Bt[N,K]^T + bias -------
// 256 threads = 4 waves (2x2); glds width-16 staging; LDS double buffer.
// BK==64 uses an XOR swizzle on the 8-element column group (r4: 16-way
// conflict fix). MODE 0: QKV scatter; MODE 1: resid+bias fp32; MODE 2: gelu.
template <int BM, int BN, int BK, int MODE>
__global__ __launch_bounds__(256) void gemm_db(
    const unsigned short* __restrict__ A, const unsigned short* __restrict__ Bt,
    const float* __restrict__ bias, const float* __restrict__ resid,
    float* __restrict__ outF, unsigned short* __restrict__ outB,
    unsigned short* __restrict__ qO, unsigned short* __restrict__ kO,
    unsigned short* __restrict__ vtO, int M, int N, int K) {
  constexpr int AT = BM / 32;
  constexpr int BT = BN / 32;
  constexpr int KS = BK / 32;
  constexpr int CA = BM * BK / 2048;
  constexpr int CB = BN * BK / 2048;
  constexpr int ASZ = BM * BK, BSZ = BN * BK;
  constexpr bool SWIZ = (BK == 64);
  __shared__ __align__(16) unsigned short As[2 * ASZ];
  __shared__ __align__(16) unsigned short Bs[2 * BSZ];
  int tid = threadIdx.x;
  int wv = tid >> 6, lane = tid & 63, quad = lane >> 4, l15 = lane & 15;
  int wm = wv >> 1, wn = wv & 1;
  int m0, n0;
  if (MODE == 1) { m0 = blockIdx.x * BM; n0 = blockIdx.y * BN; }
  else           { n0 = blockIdx.x * BN; m0 = blockIdx.y * BM; }
  fx4 acc[AT][BT];
#pragma unroll
  for (int i = 0; i < AT; ++i)
#pragma unroll
    for (int j = 0; j < BT; ++j) acc[i][j] = fx4{0.f, 0.f, 0.f, 0.f};

  int nk = K / BK;
#pragma unroll
  for (int i = 0; i < CA; ++i) {
    int e = (i * 256 + tid) * 8;
    int row = e / BK, col = e & (BK - 1);
    if (SWIZ) col = (((col >> 3) ^ (row & 7)) << 3);
    glds16(&A[(size_t)(m0 + row) * K + col], &As[(i * 256 + (tid & ~63)) * 8]);
  }
#pragma unroll
  for (int i = 0; i < CB; ++i) {
    int e = (i * 256 + tid) * 8;
    int row = e / BK, col = e & (BK - 1);
    if (SWIZ) col = (((col >> 3) ^ (row & 7)) << 3);
    glds16(&Bt[(size_t)(n0 + row) * K + col], &Bs[(i * 256 + (tid & ~63)) * 8]);
  }
  for (int kt = 0; kt < nk; ++kt) {
    int cur = kt & 1;
    __syncthreads();
    if (kt + 1 < nk) {
      int kb = (kt + 1) * BK;
      int nxt = cur ^ 1;
#pragma unroll
      for (int i = 0; i < CA; ++i) {
        int e = (i * 256 + tid) * 8;
        int row = e / BK, col = e & (BK - 1);
        if (SWIZ) col = (((col >> 3) ^ (row & 7)) << 3);
        glds16(&A[(size_t)(m0 + row) * K + kb + col],
               &As[nxt * ASZ + (i * 256 + (tid & ~63)) * 8]);
      }
#pragma unroll
      for (int i = 0; i < CB; ++i) {
        int e = (i * 256 + tid) * 8;
        int row = e / BK, col = e & (BK - 1);
        if (SWIZ) col = (((col >> 3) ^ (row & 7)) << 3);
        glds16(&Bt[(size_t)(n0 + row) * K + kb + col],
               &Bs[nxt * BSZ + (i * 256 + (tid & ~63)) * 8]);
      }
    }
#pragma unroll
    for (int ks = 0; ks < KS; ++ks) {
      s16x8 af[AT], bf[BT];
#pragma unroll
      for (int mt = 0; mt < AT; ++mt) {
        int r = wm * (BM / 2) + mt * 16 + l15;
        int c = ks * 32 + quad * 8;
        if (SWIZ) c = (((c >> 3) ^ (r & 7)) << 3);
        af[mt] = *(const s16x8*)&As[cur * ASZ + r * BK + c];
      }
#pragma unroll
      for (int nt = 0; nt < BT; ++nt) {
        int r = wn * (BN / 2) + nt * 16 + l15;
        int c = ks * 32 + quad * 8;
        if (SWIZ) c = (((c >> 3) ^ (r & 7)) << 3);
        bf[nt] = *(const s16x8*)&Bs[cur * BSZ + r * BK + c];
      }
#pragma unroll
      for (int mt = 0; mt < AT; ++mt)
#pragma unroll
        for (int nt = 0; nt < BT; ++nt)
          acc[mt][nt] = __builtin_amdgcn_mfma_f32_16x16x32_bf16(af[mt], bf[nt], acc[mt][nt], 0, 0, 0);
    }
  }

#pragma unroll
  for (int mt = 0; mt < AT; ++mt)
#pragma unroll
    for (int nt = 0; nt < BT; ++nt) {
      int mb = m0 + wm * (BM / 2) + mt * 16 + quad * 4;
      int n = n0 + wn * (BN / 2) + nt * 16 + l15;
      if (MODE == 0) {
        int which = n / C_;
        int within = n - which * C_;
        int hd = within >> 6, d = within & 63;
        int bbx = mb >> 11, t = mb & 2047;
        size_t bh = (size_t)(bbx * H_ + hd);
        float b = bias[n];
        if (which == 2) {
          // V^T: 4 consecutive t at fixed d -> one 8B packed store
          unsigned v01 = (unsigned)f2bf(acc[mt][nt][0] + b) |
                         ((unsigned)f2bf(acc[mt][nt][1] + b) << 16);
          unsigned v23 = (unsigned)f2bf(acc[mt][nt][2] + b) |
                         ((unsigned)f2bf(acc[mt][nt][3] + b) << 16);
          *(uint2*)&vtO[(bh * D_ + d) * T_ + t] = uint2{v01, v23};
        } else {
          unsigned short* dst = (which == 0) ? qO : kO;
#pragma unroll
          for (int r = 0; r < 4; ++r)
            dst[(bh * T_ + t + r) * D_ + d] = f2bf(acc[mt][nt][r] + b);
        }
      } else if (MODE == 1) {
#pragma unroll
        for (int r = 0; r < 4; ++r) {
          int m = mb + r;
          float v = acc[mt][nt][r] + bias[n];
          outF[(size_t)m * N + n] = resid[(size_t)m * N + n] + v;
        }
      } else {
#pragma unroll
        for (int r = 0; r < 4; ++r) {
          int m = mb + r;
          float v = acc[mt][nt][r] + bias[n];
          float gl = 0.5f * v * (1.f + erff(v * 0.70710678118654752f));
          outB[(size_t)m * N + n] = f2bf(gl);
        }
      }
    }
}

// ---------------- fused causal flash attention ------------------------------
// r5 structure (LDS-staged K/V, register prefetch, 2 barriers/tile) with an
// exactly-balanced qt schedule: under round-robin block->CU placement, the
// three co-resident blocks {c, 256+c, 512+c} carry qt triples summing to a
// uniform 49/50 tiles (vs 50..65 for the r5 swizzle).
__global__ __launch_bounds__(256) void attn_fused(
    const unsigned short* __restrict__ Q, const unsigned short* __restrict__ Kg,
    const unsigned short* __restrict__ Vt, unsigned short* __restrict__ Y) {
  __shared__ __align__(16) unsigned short Ks[64 * 72];
  __shared__ __align__(16) unsigned short Vs[64 * 72];
  __shared__ __align__(16) unsigned short Ps[4][16 * 72];
  int tid = threadIdx.x;
  int wv = tid >> 6, lane = tid & 63, quad = lane >> 4, l15 = lane & 15;
  int l = blockIdx.x;
  int w = l >> 8, c = l & 255;
  int i = c & 31;
  int bh = w * 8 + (c >> 5);
  int qt;
  if (w == 0)      qt = i;
  else if (w == 1) qt = (i + 16) & 31;
  else             qt = (i < 16) ? (30 - 2 * i) : (63 - 2 * i);
  int bbx = bh / H_, hh = bh - bbx * H_;
  int q0 = qt * 64;
  size_t base = (size_t)bh * T_ * D_;
  size_t vbase = (size_t)bh * D_ * T_;
  int qrow = q0 + wv * 16 + l15;
  s16x8 qf0 = *(const s16x8*)&Q[base + (size_t)qrow * D_ + quad * 8];
  s16x8 qf1 = *(const s16x8*)&Q[base + (size_t)qrow * D_ + 32 + quad * 8];
  float lsum[4];
  fx4 oacc[4];
#pragma unroll
  for (int t = 0; t < 4; ++t) {
    lsum[t] = 0.f;
    oacc[t] = fx4{0.f, 0.f, 0.f, 0.f};
  }
  int r0s = tid >> 3;
  int c8 = (tid & 7) * 8;
  uint4 ka, kc, va, vc;
  {
    ka = *(const uint4*)&Kg[base + (size_t)r0s * D_ + c8];
    kc = *(const uint4*)&Kg[base + (size_t)(r0s + 32) * D_ + c8];
    va = *(const uint4*)&Vt[vbase + (size_t)r0s * T_ + c8];
    vc = *(const uint4*)&Vt[vbase + (size_t)(r0s + 32) * T_ + c8];
  }
  for (int kb = 0; kb <= qt; ++kb) {
    int k0 = kb * 64;
    __syncthreads();
    *(uint4*)&Ks[r0s * 72 + c8] = ka;
    *(uint4*)&Ks[(r0s + 32) * 72 + c8] = kc;
    *(uint4*)&Vs[r0s * 72 + c8] = va;
    *(uint4*)&Vs[(r0s + 32) * 72 + c8] = vc;
    __syncthreads();
    if (kb < qt) {  // prefetch next tile; latency hidden behind compute below
      int kn = k0 + 64;
      ka = *(const uint4*)&Kg[base + (size_t)(kn + r0s) * D_ + c8];
      kc = *(const uint4*)&Kg[base + (size_t)(kn + r0s + 32) * D_ + c8];
      va = *(const uint4*)&Vt[vbase + (size_t)r0s * T_ + kn + c8];
      vc = *(const uint4*)&Vt[vbase + (size_t)(r0s + 32) * T_ + kn + c8];
    }
    fx4 sc[4];
#pragma unroll
    for (int nt = 0; nt < 4; ++nt) {
      sc[nt] = fx4{0.f, 0.f, 0.f, 0.f};
      s16x8 kf0 = *(const s16x8*)&Ks[(nt * 16 + l15) * 72 + quad * 8];
      s16x8 kf1 = *(const s16x8*)&Ks[(nt * 16 + l15) * 72 + 32 + quad * 8];
      sc[nt] = __builtin_amdgcn_mfma_f32_16x16x32_bf16(qf0, kf0, sc[nt], 0, 0, 0);
      sc[nt] = __builtin_amdgcn_mfma_f32_16x16x32_bf16(qf1, kf1, sc[nt], 0, 0, 0);
    }
    bool diag = (kb == qt);
    unsigned short* pw = &Ps[wv][0];
#pragma unroll
    for (int nt = 0; nt < 4; ++nt)
#pragma unroll
      for (int r = 0; r < 4; ++r) {
        float p;
        if (diag && (k0 + nt * 16 + l15) > (q0 + wv * 16 + quad * 4 + r)) {
          p = 0.f;
        } else {
          p = __expf(sc[nt][r] * 0.125f);
        }
        lsum[r] += p;
        pw[(quad * 4 + r) * 72 + nt * 16 + l15] = f2bf_trunc(p);
      }
    s16x8 pa0 = *(const s16x8*)&pw[l15 * 72 + quad * 8];
    s16x8 pa1 = *(const s16x8*)&pw[l15 * 72 + 32 + quad * 8];
#pragma unroll
    for (int nt = 0; nt < 4; ++nt) {
      s16x8 vf0 = *(const s16x8*)&Vs[(nt * 16 + l15) * 72 + quad * 8];
      s16x8 vf1 = *(const s16x8*)&Vs[(nt * 16 + l15) * 72 + 32 + quad * 8];
      oacc[nt] = __builtin_amdgcn_mfma_f32_16x16x32_bf16(pa0, vf0, oacc[nt], 0, 0, 0);
      oacc[nt] = __builtin_amdgcn_mfma_f32_16x16x32_bf16(pa1, vf1, oacc[nt], 0, 0, 0);
    }
  }
#pragma unroll
  for (int r = 0; r < 4; ++r) {
#pragma unroll
    for (int off = 1; off < 16; off <<= 1) lsum[r] += __shfl_xor(lsum[r], off);
  }
#pragma unroll
  for (int nt = 0; nt < 4; ++nt)
#pragma unroll
    for (int r = 0; r < 4; ++r) {
      float o = oacc[nt][r] / lsum[r];
      int token = bbx * T_ + q0 + wv * 16 + quad * 4 + r;
      Y[(size_t)token * C_ + hh * D_ + nt * 16 + l15] = f2bf(o);
    }
}

// ---------------- launcher --------------------------------------------------
extern "C" void kernel_launch(void* const* d_in, const int* in_sizes, int n_in,
                              void* d_out, int out_size, void* d_ws, size_t ws_size,
                              hipStream_t stream) {
  const float* x      = (const float*)d_in[0];
  const float* ln1g   = (const float*)d_in[1];
  const float* ln1b   = (const float*)d_in[2];
  const float* Wattn  = (const float*)d_in[3];
  const float* battn  = (const float*)d_in[4];
  const float* Wcproj = (const float*)d_in[5];
  const float* bcproj = (const float*)d_in[6];
  const float* ln2g   = (const float*)d_in[7];
  const float* ln2b   = (const float*)d_in[8];
  const float* Wfc    = (const float*)d_in[9];
  const float* bfc    = (const float*)d_in[10];
  const float* Wmproj = (const float*)d_in[11];
  const float* bmproj = (const float*)d_in[12];
  float* out = (float*)d_out;
  char* ws = (char*)d_ws;

  unsigned short* WattnT  = (unsigned short*)(ws + 0);          // 2304x768 bf16
  unsigned short* WcprojT = (unsigned short*)(ws + 3538944);    // 768x768
  unsigned short* WfcT    = (unsigned short*)(ws + 4718592);    // 3072x768
  unsigned short* WmprojT = (unsigned short*)(ws + 9437184);    // 768x3072
  unsigned short* hbuf    = (unsigned short*)(ws + 14155776);   // 4096x768 bf16
  unsigned short* Qb      = (unsigned short*)(ws + 20447232);   // [24,2048,64]
  unsigned short* Kb      = (unsigned short*)(ws + 26738688);   // [24,2048,64]
  unsigned short* Vtb     = (unsigned short*)(ws + 33030144);   // [24,64,2048]
  unsigned short* Yb      = (unsigned short*)(ws + 39321600);   // 4096x768 bf16
  float*          x1      = (float*)(ws + 45613056);            // 4096x768 fp32
  unsigned short* Ab      = (unsigned short*)(ws + 58195968);   // 4096x3072 bf16

  transpose_cast<<<dim3(2304 / 32, 768 / 32), 256, 0, stream>>>(Wattn, WattnT, 768, 2304);
  transpose_cast<<<dim3(768 / 32, 768 / 32), 256, 0, stream>>>(Wcproj, WcprojT, 768, 768);
  transpose_cast<<<dim3(3072 / 32, 768 / 32), 256, 0, stream>>>(Wfc, WfcT, 768, 3072);
  transpose_cast<<<dim3(768 / 32, 3072 / 32), 256, 0, stream>>>(Wmproj, WmprojT, 3072, 768);

  layernorm_bf16<<<4096, 256, 0, stream>>>(x, ln1g, ln1b, hbuf);

  gemm_db<128, 128, 32, 0><<<dim3(2304 / 128, 4096 / 128), 256, 0, stream>>>(
      hbuf, WattnT, battn, nullptr, nullptr, nullptr, Qb, Kb, Vtb, 4096, 2304, 768);

  attn_fused<<<768, 256, 0, stream>>>(Qb, Kb, Vtb, Yb);

  // cproj: x1 = x + Yb*Wc + bias  (m-tile fastest in grid.x for L2 locality)
  gemm_db<128, 64, 64, 1><<<dim3(4096 / 128, 768 / 64), 256, 0, stream>>>(
      Yb, WcprojT, bcproj, x, x1, nullptr, nullptr, nullptr, nullptr, 4096, 768, 768);

  layernorm_bf16<<<4096, 256, 0, stream>>>(x1, ln2g, ln2b, hbuf);

  gemm_db<128, 128, 32, 2><<<dim3(3072 / 128, 4096 / 128), 256, 0, stream>>>(
      hbuf, WfcT, bfc, nullptr, nullptr, Ab, nullptr, nullptr, nullptr, 4096, 3072, 768);

  // mproj: out = x1 + Ab*Wm + bias
  gemm_db<128, 64, 64, 1><<<dim3(4096 / 128, 768 / 64), 256, 0, stream>>>(
      Ab, WmprojT, bmproj, x1, out, nullptr, nullptr, nullptr, nullptr, 4096, 768, 3072);
}

// Round 8
// 271.205 us; speedup vs baseline: 1.3502x; 1.0034x over previous
//
#include <hip/hip_runtime.h>
#include <cstdint>
#include <cstddef>

#define B_ 2
#define T_ 2048
#define C_ 768
#define H_ 12
#define D_ 64

typedef __attribute__((ext_vector_type(8))) short s16x8;
typedef __attribute__((ext_vector_type(4))) float fx4;

static __device__ __forceinline__ unsigned short f2bf(float f) {
  unsigned u = __builtin_bit_cast(unsigned, f);
  unsigned r = u + 0x7fffu + ((u >> 16) & 1u);
  return (unsigned short)(r >> 16);
}
static __device__ __forceinline__ unsigned short f2bf_trunc(float f) {
  return (unsigned short)(__builtin_bit_cast(unsigned, f) >> 16);
}

static __device__ __forceinline__ void glds16(const unsigned short* g, unsigned short* l) {
  __builtin_amdgcn_global_load_lds(
      (const __attribute__((address_space(1))) void*)(g),
      (__attribute__((address_space(3))) void*)(l), 16, 0, 0);
}

// ---------------- fused prep: 4 weight transposes + LN1 in one launch -------
__global__ __launch_bounds__(256) void prep(
    const float* __restrict__ Wattn, const float* __restrict__ Wcproj,
    const float* __restrict__ Wfc, const float* __restrict__ Wmproj,
    unsigned short* __restrict__ WattnT, unsigned short* __restrict__ WcprojT,
    unsigned short* __restrict__ WfcT, unsigned short* __restrict__ WmprojT,
    const float* __restrict__ X, const float* __restrict__ g,
    const float* __restrict__ bb, unsigned short* __restrict__ O) {
  __shared__ float tile[32][33];
  __shared__ float ps[8];
  int bid = blockIdx.x, tid = threadIdx.x;
  if (bid < 6912) {
    const float* W; unsigned short* Wt; int R, C, idx;
    if (bid < 1728)      { W = Wattn;  Wt = WattnT;  R = 768;  C = 2304; idx = bid; }
    else if (bid < 2304) { W = Wcproj; Wt = WcprojT; R = 768;  C = 768;  idx = bid - 1728; }
    else if (bid < 4608) { W = Wfc;    Wt = WfcT;    R = 768;  C = 3072; idx = bid - 2304; }
    else                 { W = Wmproj; Wt = WmprojT; R = 3072; C = 768;  idx = bid - 4608; }
    int ct = C >> 5;
    int c0 = (idx % ct) * 32, r0 = (idx / ct) * 32;
    int tx = tid & 31, ty = tid >> 5;
#pragma unroll
    for (int i = 0; i < 4; ++i)
      tile[ty + i * 8][tx] = W[(size_t)(r0 + ty + i * 8) * C + (c0 + tx)];
    __syncthreads();
#pragma unroll
    for (int i = 0; i < 4; ++i)
      Wt[(size_t)(c0 + ty + i * 8) * R + (r0 + tx)] = f2bf(tile[tx][ty + i * 8]);
  } else {
    int row = bid - 6912;
    const float* xr = X + (size_t)row * C_;
    float v0 = xr[tid], v1 = xr[tid + 256], v2 = xr[tid + 512];
    float s = v0 + v1 + v2;
    float s2 = v0 * v0 + v1 * v1 + v2 * v2;
#pragma unroll
    for (int off = 1; off < 64; off <<= 1) {
      s += __shfl_xor(s, off);
      s2 += __shfl_xor(s2, off);
    }
    int wv = tid >> 6;
    if ((tid & 63) == 0) { ps[wv] = s; ps[wv + 4] = s2; }
    __syncthreads();
    s = ps[0] + ps[1] + ps[2] + ps[3];
    s2 = ps[4] + ps[5] + ps[6] + ps[7];
    float mu = s * (1.f / C_);
    float var = s2 * (1.f / C_) - mu * mu;
    float rstd = rsqrtf(var + 1e-5f);
    unsigned short* orow = O + (size_t)row * C_;
    orow[tid]       = f2bf((v0 - mu) * rstd * g[tid]       + bb[tid]);
    orow[tid + 256] = f2bf((v1 - mu) * rstd * g[tid + 256] + bb[tid + 256]);
    orow[tid + 512] = f2bf((v2 - mu) * rstd * g[tid + 512] + bb[tid + 512]);
  }
}

// ---------------- layernorm fp32 -> bf16 ------------------------------------
__global__ __launch_bounds__(256) void layernorm_bf16(
    const float* __restrict__ X, const float* __restrict__ g,
    const float* __restrict__ bb, unsigned short* __restrict__ O) {
  int row = blockIdx.x, tid = threadIdx.x;
  const float* xr = X + (size_t)row * C_;
  float v0 = xr[tid], v1 = xr[tid + 256], v2 = xr[tid + 512];
  float s = v0 + v1 + v2;
  float s2 = v0 * v0 + v1 * v1 + v2 * v2;
#pragma unroll
  for (int off = 1; off < 64; off <<= 1) {
    s += __shfl_xor(s, off);
    s2 += __shfl_xor(s2, off);
  }
  __shared__ float ps[8];
  int wv = tid >> 6;
  if ((tid & 63) == 0) { ps[wv] = s; ps[wv + 4] = s2; }
  __syncthreads();
  s = ps[0] + ps[1] + ps[2] + ps[3];
  s2 = ps[4] + ps[5] + ps[6] + ps[7];
  float mu = s * (1.f / C_);
  float var = s2 * (1.f / C_) - mu * mu;
  float rstd = rsqrtf(var + 1e-5f);
  unsigned short* orow = O + (size_t)row * C_;
  orow[tid]       = f2bf((v0 - mu) * rstd * g[tid]       + bb[tid]);
  orow[tid + 256] = f2bf((v1 - mu) * rstd * g[tid + 256] + bb[tid + 256]);
  orow[tid + 512] = f2bf((v2 - mu) * rstd * g[tid + 512] + bb[tid + 512]);
}

// ---------------- double-buffered GEMM: C = A[M,K] * Bt[N,K]^T + bias -------
template <int BM, int BN, int BK, int MODE>
__global__ __launch_bounds__(256) void gemm_db(
    const unsigned short* __restrict__ A, const unsigned short* __restrict__ Bt,
    const float* __restrict__ bias, const float* __restrict__ resid,
    float* __restrict__ outF, unsigned short* __restrict__ outB,
    unsigned short* __restrict__ qO, unsigned short* __restrict__ kO,
    unsigned short* __restrict__ vtO, int M, int N, int K) {
  constexpr int AT = BM / 32;
  constexpr int BT = BN / 32;
  constexpr int KS = BK / 32;
  constexpr int CA = BM * BK / 2048;
  constexpr int CB = BN * BK / 2048;
  constexpr int ASZ = BM * BK, BSZ = BN * BK;
  constexpr bool SWIZ = (BK == 64);
  __shared__ __align__(16) unsigned short As[2 * ASZ];
  __shared__ __align__(16) unsigned short Bs[2 * BSZ];
  int tid = threadIdx.x;
  int wv = tid >> 6, lane = tid & 63, quad = lane >> 4, l15 = lane & 15;
  int wm = wv >> 1, wn = wv & 1;
  int m0, n0;
  if (MODE == 1) { m0 = blockIdx.x * BM; n0 = blockIdx.y * BN; }
  else           { n0 = blockIdx.x * BN; m0 = blockIdx.y * BM; }
  fx4 acc[AT][BT];
#pragma unroll
  for (int i = 0; i < AT; ++i)
#pragma unroll
    for (int j = 0; j < BT; ++j) acc[i][j] = fx4{0.f, 0.f, 0.f, 0.f};

  int nk = K / BK;
#pragma unroll
  for (int i = 0; i < CA; ++i) {
    int e = (i * 256 + tid) * 8;
    int row = e / BK, col = e & (BK - 1);
    if (SWIZ) col = (((col >> 3) ^ (row & 7)) << 3);
    glds16(&A[(size_t)(m0 + row) * K + col], &As[(i * 256 + (tid & ~63)) * 8]);
  }
#pragma unroll
  for (int i = 0; i < CB; ++i) {
    int e = (i * 256 + tid) * 8;
    int row = e / BK, col = e & (BK - 1);
    if (SWIZ) col = (((col >> 3) ^ (row & 7)) << 3);
    glds16(&Bt[(size_t)(n0 + row) * K + col], &Bs[(i * 256 + (tid & ~63)) * 8]);
  }
  for (int kt = 0; kt < nk; ++kt) {
    int cur = kt & 1;
    __syncthreads();
    if (kt + 1 < nk) {
      int kb = (kt + 1) * BK;
      int nxt = cur ^ 1;
#pragma unroll
      for (int i = 0; i < CA; ++i) {
        int e = (i * 256 + tid) * 8;
        int row = e / BK, col = e & (BK - 1);
        if (SWIZ) col = (((col >> 3) ^ (row & 7)) << 3);
        glds16(&A[(size_t)(m0 + row) * K + kb + col],
               &As[nxt * ASZ + (i * 256 + (tid & ~63)) * 8]);
      }
#pragma unroll
      for (int i = 0; i < CB; ++i) {
        int e = (i * 256 + tid) * 8;
        int row = e / BK, col = e & (BK - 1);
        if (SWIZ) col = (((col >> 3) ^ (row & 7)) << 3);
        glds16(&Bt[(size_t)(n0 + row) * K + kb + col],
               &Bs[nxt * BSZ + (i * 256 + (tid & ~63)) * 8]);
      }
    }
#pragma unroll
    for (int ks = 0; ks < KS; ++ks) {
      s16x8 af[AT], bf[BT];
#pragma unroll
      for (int mt = 0; mt < AT; ++mt) {
        int r = wm * (BM / 2) + mt * 16 + l15;
        int c = ks * 32 + quad * 8;
        if (SWIZ) c = (((c >> 3) ^ (r & 7)) << 3);
        af[mt] = *(const s16x8*)&As[cur * ASZ + r * BK + c];
      }
#pragma unroll
      for (int nt = 0; nt < BT; ++nt) {
        int r = wn * (BN / 2) + nt * 16 + l15;
        int c = ks * 32 + quad * 8;
        if (SWIZ) c = (((c >> 3) ^ (r & 7)) << 3);
        bf[nt] = *(const s16x8*)&Bs[cur * BSZ + r * BK + c];
      }
#pragma unroll
      for (int mt = 0; mt < AT; ++mt)
#pragma unroll
        for (int nt = 0; nt < BT; ++nt)
          acc[mt][nt] = __builtin_amdgcn_mfma_f32_16x16x32_bf16(af[mt], bf[nt], acc[mt][nt], 0, 0, 0);
    }
  }

#pragma unroll
  for (int mt = 0; mt < AT; ++mt)
#pragma unroll
    for (int nt = 0; nt < BT; ++nt) {
      int mb = m0 + wm * (BM / 2) + mt * 16 + quad * 4;
      int n = n0 + wn * (BN / 2) + nt * 16 + l15;
      if (MODE == 0) {
        int which = n / C_;
        int within = n - which * C_;
        int hd = within >> 6, d = within & 63;
        int bbx = mb >> 11, t = mb & 2047;
        size_t bh = (size_t)(bbx * H_ + hd);
        float b = bias[n];
        if (which == 2) {
          unsigned v01 = (unsigned)f2bf(acc[mt][nt][0] + b) |
                         ((unsigned)f2bf(acc[mt][nt][1] + b) << 16);
          unsigned v23 = (unsigned)f2bf(acc[mt][nt][2] + b) |
                         ((unsigned)f2bf(acc[mt][nt][3] + b) << 16);
          *(uint2*)&vtO[(bh * D_ + d) * T_ + t] = uint2{v01, v23};
        } else {
          unsigned short* dst = (which == 0) ? qO : kO;
#pragma unroll
          for (int r = 0; r < 4; ++r)
            dst[(bh * T_ + t + r) * D_ + d] = f2bf(acc[mt][nt][r] + b);
        }
      } else if (MODE == 1) {
#pragma unroll
        for (int r = 0; r < 4; ++r) {
          int m = mb + r;
          float v = acc[mt][nt][r] + bias[n];
          outF[(size_t)m * N + n] = resid[(size_t)m * N + n] + v;
        }
      } else {
#pragma unroll
        for (int r = 0; r < 4; ++r) {
          int m = mb + r;
          float v = acc[mt][nt][r] + bias[n];
          float gl = 0.5f * v * (1.f + erff(v * 0.70710678118654752f));
          outB[(size_t)m * N + n] = f2bf(gl);
        }
      }
    }
}

// ---------------- fused causal flash attention ------------------------------
__global__ __launch_bounds__(256) void attn_fused(
    const unsigned short* __restrict__ Q, const unsigned short* __restrict__ Kg,
    const unsigned short* __restrict__ Vt, unsigned short* __restrict__ Y) {
  __shared__ __align__(16) unsigned short Ks[64 * 72];
  __shared__ __align__(16) unsigned short Vs[64 * 72];
  __shared__ __align__(16) unsigned short Ps[4][16 * 72];
  int tid = threadIdx.x;
  int wv = tid >> 6, lane = tid & 63, quad = lane >> 4, l15 = lane & 15;
  int l = blockIdx.x;
  int w = l >> 8, c = l & 255;
  int i = c & 31;
  int bh = w * 8 + (c >> 5);
  int qt;
  if (w == 0)      qt = i;
  else if (w == 1) qt = (i + 16) & 31;
  else             qt = (i < 16) ? (30 - 2 * i) : (63 - 2 * i);
  int bbx = bh / H_, hh = bh - bbx * H_;
  int q0 = qt * 64;
  size_t base = (size_t)bh * T_ * D_;
  size_t vbase = (size_t)bh * D_ * T_;
  int qrow = q0 + wv * 16 + l15;
  s16x8 qf0 = *(const s16x8*)&Q[base + (size_t)qrow * D_ + quad * 8];
  s16x8 qf1 = *(const s16x8*)&Q[base + (size_t)qrow * D_ + 32 + quad * 8];
  float lsum[4];
  fx4 oacc[4];
#pragma unroll
  for (int t = 0; t < 4; ++t) {
    lsum[t] = 0.f;
    oacc[t] = fx4{0.f, 0.f, 0.f, 0.f};
  }
  int r0s = tid >> 3;
  int c8 = (tid & 7) * 8;
  uint4 ka, kc, va, vc;
  {
    ka = *(const uint4*)&Kg[base + (size_t)r0s * D_ + c8];
    kc = *(const uint4*)&Kg[base + (size_t)(r0s + 32) * D_ + c8];
    va = *(const uint4*)&Vt[vbase + (size_t)r0s * T_ + c8];
    vc = *(const uint4*)&Vt[vbase + (size_t)(r0s + 32) * T_ + c8];
  }
  for (int kb = 0; kb <= qt; ++kb) {
    int k0 = kb * 64;
    __syncthreads();
    *(uint4*)&Ks[r0s * 72 + c8] = ka;
    *(uint4*)&Ks[(r0s + 32) * 72 + c8] = kc;
    *(uint4*)&Vs[r0s * 72 + c8] = va;
    *(uint4*)&Vs[(r0s + 32) * 72 + c8] = vc;
    __syncthreads();
    if (kb < qt) {
      int kn = k0 + 64;
      ka = *(const uint4*)&Kg[base + (size_t)(kn + r0s) * D_ + c8];
      kc = *(const uint4*)&Kg[base + (size_t)(kn + r0s + 32) * D_ + c8];
      va = *(const uint4*)&Vt[vbase + (size_t)r0s * T_ + kn + c8];
      vc = *(const uint4*)&Vt[vbase + (size_t)(r0s + 32) * T_ + kn + c8];
    }
    fx4 sc[4];
#pragma unroll
    for (int nt = 0; nt < 4; ++nt) {
      sc[nt] = fx4{0.f, 0.f, 0.f, 0.f};
      s16x8 kf0 = *(const s16x8*)&Ks[(nt * 16 + l15) * 72 + quad * 8];
      s16x8 kf1 = *(const s16x8*)&Ks[(nt * 16 + l15) * 72 + 32 + quad * 8];
      sc[nt] = __builtin_amdgcn_mfma_f32_16x16x32_bf16(qf0, kf0, sc[nt], 0, 0, 0);
      sc[nt] = __builtin_amdgcn_mfma_f32_16x16x32_bf16(qf1, kf1, sc[nt], 0, 0, 0);
    }
    bool diag = (kb == qt);
    unsigned short* pw = &Ps[wv][0];
#pragma unroll
    for (int nt = 0; nt < 4; ++nt)
#pragma unroll
      for (int r = 0; r < 4; ++r) {
        float p;
        if (diag && (k0 + nt * 16 + l15) > (q0 + wv * 16 + quad * 4 + r)) {
          p = 0.f;
        } else {
          p = __expf(sc[nt][r] * 0.125f);
        }
        lsum[r] += p;
        pw[(quad * 4 + r) * 72 + nt * 16 + l15] = f2bf_trunc(p);
      }
    s16x8 pa0 = *(const s16x8*)&pw[l15 * 72 + quad * 8];
    s16x8 pa1 = *(const s16x8*)&pw[l15 * 72 + 32 + quad * 8];
#pragma unroll
    for (int nt = 0; nt < 4; ++nt) {
      s16x8 vf0 = *(const s16x8*)&Vs[(nt * 16 + l15) * 72 + quad * 8];
      s16x8 vf1 = *(const s16x8*)&Vs[(nt * 16 + l15) * 72 + 32 + quad * 8];
      oacc[nt] = __builtin_amdgcn_mfma_f32_16x16x32_bf16(pa0, vf0, oacc[nt], 0, 0, 0);
      oacc[nt] = __builtin_amdgcn_mfma_f32_16x16x32_bf16(pa1, vf1, oacc[nt], 0, 0, 0);
    }
  }
#pragma unroll
  for (int r = 0; r < 4; ++r) {
#pragma unroll
    for (int off = 1; off < 16; off <<= 1) lsum[r] += __shfl_xor(lsum[r], off);
  }
#pragma unroll
  for (int nt = 0; nt < 4; ++nt)
#pragma unroll
    for (int r = 0; r < 4; ++r) {
      float o = oacc[nt][r] / lsum[r];
      int token = bbx * T_ + q0 + wv * 16 + quad * 4 + r;
      Y[(size_t)token * C_ + hh * D_ + nt * 16 + l15] = f2bf(o);
    }
}

// ---------------- launcher --------------------------------------------------
extern "C" void kernel_launch(void* const* d_in, const int* in_sizes, int n_in,
                              void* d_out, int out_size, void* d_ws, size_t ws_size,
                              hipStream_t stream) {
  const float* x      = (const float*)d_in[0];
  const float* ln1g   = (const float*)d_in[1];
  const float* ln1b   = (const float*)d_in[2];
  const float* Wattn  = (const float*)d_in[3];
  const float* battn  = (const float*)d_in[4];
  const float* Wcproj = (const float*)d_in[5];
  const float* bcproj = (const float*)d_in[6];
  const float* ln2g   = (const float*)d_in[7];
  const float* ln2b   = (const float*)d_in[8];
  const float* Wfc    = (const float*)d_in[9];
  const float* bfc    = (const float*)d_in[10];
  const float* Wmproj = (const float*)d_in[11];
  const float* bmproj = (const float*)d_in[12];
  float* out = (float*)d_out;
  char* ws = (char*)d_ws;

  unsigned short* WattnT  = (unsigned short*)(ws + 0);
  unsigned short* WcprojT = (unsigned short*)(ws + 3538944);
  unsigned short* WfcT    = (unsigned short*)(ws + 4718592);
  unsigned short* WmprojT = (unsigned short*)(ws + 9437184);
  unsigned short* hbuf    = (unsigned short*)(ws + 14155776);
  unsigned short* Qb      = (unsigned short*)(ws + 20447232);
  unsigned short* Kb      = (unsigned short*)(ws + 26738688);
  unsigned short* Vtb     = (unsigned short*)(ws + 33030144);
  unsigned short* Yb      = (unsigned short*)(ws + 39321600);
  float*          x1      = (float*)(ws + 45613056);
  unsigned short* Ab      = (unsigned short*)(ws + 58195968);

  prep<<<11008, 256, 0, stream>>>(Wattn, Wcproj, Wfc, Wmproj,
                                  WattnT, WcprojT, WfcT, WmprojT,
                                  x, ln1g, ln1b, hbuf);

  // qkv: BM=128 BN=96 BK=64 -> grid (24,32) = 768 blocks = 3/CU uniform
  gemm_db<128, 96, 64, 0><<<dim3(24, 32), 256, 0, stream>>>(
      hbuf, WattnT, battn, nullptr, nullptr, nullptr, Qb, Kb, Vtb, 4096, 2304, 768);

  attn_fused<<<768, 256, 0, stream>>>(Qb, Kb, Vtb, Yb);

  // cproj: BM=128 BN=96 -> grid (32,8) = 256 blocks = 1/CU uniform
  gemm_db<128, 96, 64, 1><<<dim3(32, 8), 256, 0, stream>>>(
      Yb, WcprojT, bcproj, x, x1, nullptr, nullptr, nullptr, nullptr, 4096, 768, 768);

  layernorm_bf16<<<4096, 256, 0, stream>>>(x1, ln2g, ln2b, hbuf);

  gemm_db<128, 128, 32, 2><<<dim3(24, 32), 256, 0, stream>>>(
      hbuf, WfcT, bfc, nullptr, nullptr, Ab, nullptr, nullptr, nullptr, 4096, 3072, 768);

  // mproj: BM=128 BN=96 -> grid (32,8) = 256 blocks = 1/CU uniform
  gemm_db<128, 96, 64, 1><<<dim3(32, 8), 256, 0, stream>>>(
      Ab, WmprojT, bmproj, x1, out, nullptr, nullptr, nullptr, nullptr, 4096, 768, 3072);
}

// Round 10
// 259.284 us; speedup vs baseline: 1.4123x; 1.0460x over previous
//
#include <hip/hip_runtime.h>
#include <cstdint>
#include <cstddef>

#define B_ 2
#define T_ 2048
#define C_ 768
#define H_ 12
#define D_ 64

typedef __attribute__((ext_vector_type(8))) short s16x8;
typedef __attribute__((ext_vector_type(4))) float fx4;

static __device__ __forceinline__ unsigned short f2bf(float f) {
  unsigned u = __builtin_bit_cast(unsigned, f);
  unsigned r = u + 0x7fffu + ((u >> 16) & 1u);
  return (unsigned short)(r >> 16);
}
static __device__ __forceinline__ unsigned short f2bf_trunc(float f) {
  return (unsigned short)(__builtin_bit_cast(unsigned, f) >> 16);
}

static __device__ __forceinline__ void glds16(const unsigned short* g, unsigned short* l) {
  __builtin_amdgcn_global_load_lds(
      (const __attribute__((address_space(1))) void*)(g),
      (__attribute__((address_space(3))) void*)(l), 16, 0, 0);
}

// ---------------- fused prep: 4 weight transposes + LN1 in one launch -------
__global__ __launch_bounds__(256) void prep(
    const float* __restrict__ Wattn, const float* __restrict__ Wcproj,
    const float* __restrict__ Wfc, const float* __restrict__ Wmproj,
    unsigned short* __restrict__ WattnT, unsigned short* __restrict__ WcprojT,
    unsigned short* __restrict__ WfcT, unsigned short* __restrict__ WmprojT,
    const float* __restrict__ X, const float* __restrict__ g,
    const float* __restrict__ bb, unsigned short* __restrict__ O) {
  __shared__ float tile[32][33];
  __shared__ float ps[8];
  int bid = blockIdx.x, tid = threadIdx.x;
  if (bid < 6912) {
    const float* W; unsigned short* Wt; int R, C, idx;
    if (bid < 1728)      { W = Wattn;  Wt = WattnT;  R = 768;  C = 2304; idx = bid; }
    else if (bid < 2304) { W = Wcproj; Wt = WcprojT; R = 768;  C = 768;  idx = bid - 1728; }
    else if (bid < 4608) { W = Wfc;    Wt = WfcT;    R = 768;  C = 3072; idx = bid - 2304; }
    else                 { W = Wmproj; Wt = WmprojT; R = 3072; C = 768;  idx = bid - 4608; }
    int ct = C >> 5;
    int c0 = (idx % ct) * 32, r0 = (idx / ct) * 32;
    int tx = tid & 31, ty = tid >> 5;
#pragma unroll
    for (int i = 0; i < 4; ++i)
      tile[ty + i * 8][tx] = W[(size_t)(r0 + ty + i * 8) * C + (c0 + tx)];
    __syncthreads();
#pragma unroll
    for (int i = 0; i < 4; ++i)
      Wt[(size_t)(c0 + ty + i * 8) * R + (r0 + tx)] = f2bf(tile[tx][ty + i * 8]);
  } else {
    int row = bid - 6912;
    const float* xr = X + (size_t)row * C_;
    float v0 = xr[tid], v1 = xr[tid + 256], v2 = xr[tid + 512];
    float s = v0 + v1 + v2;
    float s2 = v0 * v0 + v1 * v1 + v2 * v2;
#pragma unroll
    for (int off = 1; off < 64; off <<= 1) {
      s += __shfl_xor(s, off);
      s2 += __shfl_xor(s2, off);
    }
    int wv = tid >> 6;
    if ((tid & 63) == 0) { ps[wv] = s; ps[wv + 4] = s2; }
    __syncthreads();
    s = ps[0] + ps[1] + ps[2] + ps[3];
    s2 = ps[4] + ps[5] + ps[6] + ps[7];
    float mu = s * (1.f / C_);
    float var = s2 * (1.f / C_) - mu * mu;
    float rstd = rsqrtf(var + 1e-5f);
    unsigned short* orow = O + (size_t)row * C_;
    orow[tid]       = f2bf((v0 - mu) * rstd * g[tid]       + bb[tid]);
    orow[tid + 256] = f2bf((v1 - mu) * rstd * g[tid + 256] + bb[tid + 256]);
    orow[tid + 512] = f2bf((v2 - mu) * rstd * g[tid + 512] + bb[tid + 512]);
  }
}

// ---------------- layernorm fp32 -> bf16 ------------------------------------
__global__ __launch_bounds__(256) void layernorm_bf16(
    const float* __restrict__ X, const float* __restrict__ g,
    const float* __restrict__ bb, unsigned short* __restrict__ O) {
  int row = blockIdx.x, tid = threadIdx.x;
  const float* xr = X + (size_t)row * C_;
  float v0 = xr[tid], v1 = xr[tid + 256], v2 = xr[tid + 512];
  float s = v0 + v1 + v2;
  float s2 = v0 * v0 + v1 * v1 + v2 * v2;
#pragma unroll
  for (int off = 1; off < 64; off <<= 1) {
    s += __shfl_xor(s, off);
    s2 += __shfl_xor(s2, off);
  }
  __shared__ float ps[8];
  int wv = tid >> 6;
  if ((tid & 63) == 0) { ps[wv] = s; ps[wv + 4] = s2; }
  __syncthreads();
  s = ps[0] + ps[1] + ps[2] + ps[3];
  s2 = ps[4] + ps[5] + ps[6] + ps[7];
  float mu = s * (1.f / C_);
  float var = s2 * (1.f / C_) - mu * mu;
  float rstd = rsqrtf(var + 1e-5f);
  unsigned short* orow = O + (size_t)row * C_;
  orow[tid]       = f2bf((v0 - mu) * rstd * g[tid]       + bb[tid]);
  orow[tid + 256] = f2bf((v1 - mu) * rstd * g[tid + 256] + bb[tid + 256]);
  orow[tid + 512] = f2bf((v2 - mu) * rstd * g[tid + 512] + bb[tid + 512]);
}

// ---------------- reduce: out = x1 + P0 + P1 + bias (float4) ----------------
// one float4 per thread; 4096*768 fp32 = 786432 float4 -> grid 3072 x 256
__global__ __launch_bounds__(256) void reduce_out(
    const float* __restrict__ x1, const float* __restrict__ P,
    const float* __restrict__ bias, float* __restrict__ out) {
  int idx = blockIdx.x * 256 + threadIdx.x;
  float4 a = ((const float4*)x1)[idx];
  float4 p = ((const float4*)P)[idx];
  float4 q = ((const float4*)(P + (size_t)4096 * 768))[idx];
  float4 b = ((const float4*)bias)[idx % 192];
  float4 o;
  o.x = a.x + p.x + q.x + b.x;
  o.y = a.y + p.y + q.y + b.y;
  o.z = a.z + p.z + q.z + b.z;
  o.w = a.w + p.w + q.w + b.w;
  ((float4*)out)[idx] = o;
}

// ---------------- double-buffered GEMM: C = A[M,K-chunk] * Bt^T + bias ------
// 256 threads = 4 waves (2x2); glds width-16 staging; LDS double buffer.
// BK==64 XOR-swizzles the 8-elem column group (16-way conflict fix, r4/r5).
// blockIdx.z * KC picks the K chunk (KC==K when not split).
// MODE 0: QKV scatter; MODE 1: resid+bias fp32 (m-fastest grid);
// MODE 2: gelu bf16; MODE 3: raw fp32 partial to outF + z*M*N (m-fastest).
template <int BM, int BN, int BK, int MODE>
__global__ __launch_bounds__(256) void gemm_db(
    const unsigned short* __restrict__ A, const unsigned short* __restrict__ Bt,
    const float* __restrict__ bias, const float* __restrict__ resid,
    float* __restrict__ outF, unsigned short* __restrict__ outB,
    unsigned short* __restrict__ qO, unsigned short* __restrict__ kO,
    unsigned short* __restrict__ vtO, int M, int N, int K, int KC) {
  constexpr int AT = BM / 32;
  constexpr int BT = BN / 32;
  constexpr int KS = BK / 32;
  constexpr int ACH = BM * BK / 8;   // 16B lane-chunks for A stage
  constexpr int BCH = BN * BK / 8;
  constexpr int ASZ = BM * BK, BSZ = BN * BK;
  constexpr bool SWIZ = (BK == 64);
  __shared__ __align__(16) unsigned short As[2 * ASZ];
  __shared__ __align__(16) unsigned short Bs[2 * BSZ];
  int tid = threadIdx.x;
  int wv = tid >> 6, lane = tid & 63, quad = lane >> 4, l15 = lane & 15;
  int wm = wv >> 1, wn = wv & 1;
  int m0, n0;
  if (MODE == 1 || MODE == 3) { m0 = blockIdx.x * BM; n0 = blockIdx.y * BN; }
  else                        { n0 = blockIdx.x * BN; m0 = blockIdx.y * BM; }
  const unsigned short* Ak = A + (size_t)blockIdx.z * KC;
  const unsigned short* Bk = Bt + (size_t)blockIdx.z * KC;
  fx4 acc[AT][BT];
#pragma unroll
  for (int i = 0; i < AT; ++i)
#pragma unroll
    for (int j = 0; j < BT; ++j) acc[i][j] = fx4{0.f, 0.f, 0.f, 0.f};

  int nk = KC / BK;
#pragma unroll
  for (int i0 = 0; i0 < ACH; i0 += 256)
    if (ACH - i0 >= 256 || tid < ACH - i0) {
      int e = (i0 + tid) * 8;
      int row = e / BK, col = e & (BK - 1);
      if (SWIZ) col = (((col >> 3) ^ (row & 7)) << 3);
      glds16(&Ak[(size_t)(m0 + row) * K + col], &As[(i0 + (tid & ~63)) * 8]);
    }
#pragma unroll
  for (int i0 = 0; i0 < BCH; i0 += 256)
    if (BCH - i0 >= 256 || tid < BCH - i0) {
      int e = (i0 + tid) * 8;
      int row = e / BK, col = e & (BK - 1);
      if (SWIZ) col = (((col >> 3) ^ (row & 7)) << 3);
      glds16(&Bk[(size_t)(n0 + row) * K + col], &Bs[(i0 + (tid & ~63)) * 8]);
    }
  for (int kt = 0; kt < nk; ++kt) {
    int cur = kt & 1;
    __syncthreads();
    if (kt + 1 < nk) {
      int kb = (kt + 1) * BK;
      int nxt = cur ^ 1;
#pragma unroll
      for (int i0 = 0; i0 < ACH; i0 += 256)
        if (ACH - i0 >= 256 || tid < ACH - i0) {
          int e = (i0 + tid) * 8;
          int row = e / BK, col = e & (BK - 1);
          if (SWIZ) col = (((col >> 3) ^ (row & 7)) << 3);
          glds16(&Ak[(size_t)(m0 + row) * K + kb + col],
                 &As[nxt * ASZ + (i0 + (tid & ~63)) * 8]);
        }
#pragma unroll
      for (int i0 = 0; i0 < BCH; i0 += 256)
        if (BCH - i0 >= 256 || tid < BCH - i0) {
          int e = (i0 + tid) * 8;
          int row = e / BK, col = e & (BK - 1);
          if (SWIZ) col = (((col >> 3) ^ (row & 7)) << 3);
          glds16(&Bk[(size_t)(n0 + row) * K + kb + col],
                 &Bs[nxt * BSZ + (i0 + (tid & ~63)) * 8]);
        }
    }
#pragma unroll
    for (int ks = 0; ks < KS; ++ks) {
      s16x8 af[AT], bf[BT];
#pragma unroll
      for (int mt = 0; mt < AT; ++mt) {
        int r = wm * (BM / 2) + mt * 16 + l15;
        int c = ks * 32 + quad * 8;
        if (SWIZ) c = (((c >> 3) ^ (r & 7)) << 3);
        af[mt] = *(const s16x8*)&As[cur * ASZ + r * BK + c];
      }
#pragma unroll
      for (int nt = 0; nt < BT; ++nt) {
        int r = wn * (BN / 2) + nt * 16 + l15;
        int c = ks * 32 + quad * 8;
        if (SWIZ) c = (((c >> 3) ^ (r & 7)) << 3);
        bf[nt] = *(const s16x8*)&Bs[cur * BSZ + r * BK + c];
      }
#pragma unroll
      for (int mt = 0; mt < AT; ++mt)
#pragma unroll
        for (int nt = 0; nt < BT; ++nt)
          acc[mt][nt] = __builtin_amdgcn_mfma_f32_16x16x32_bf16(af[mt], bf[nt], acc[mt][nt], 0, 0, 0);
    }
  }

#pragma unroll
  for (int mt = 0; mt < AT; ++mt)
#pragma unroll
    for (int nt = 0; nt < BT; ++nt) {
      int mb = m0 + wm * (BM / 2) + mt * 16 + quad * 4;
      int n = n0 + wn * (BN / 2) + nt * 16 + l15;
      if (MODE == 0) {
        int which = n / C_;
        int within = n - which * C_;
        int hd = within >> 6, d = within & 63;
        int bbx = mb >> 11, t = mb & 2047;
        size_t bh = (size_t)(bbx * H_ + hd);
        float b = bias[n];
        if (which == 2) {
          unsigned v01 = (unsigned)f2bf(acc[mt][nt][0] + b) |
                         ((unsigned)f2bf(acc[mt][nt][1] + b) << 16);
          unsigned v23 = (unsigned)f2bf(acc[mt][nt][2] + b) |
                         ((unsigned)f2bf(acc[mt][nt][3] + b) << 16);
          *(uint2*)&vtO[(bh * D_ + d) * T_ + t] = uint2{v01, v23};
        } else {
          unsigned short* dst = (which == 0) ? qO : kO;
#pragma unroll
          for (int r = 0; r < 4; ++r)
            dst[(bh * T_ + t + r) * D_ + d] = f2bf(acc[mt][nt][r] + b);
        }
      } else if (MODE == 1) {
#pragma unroll
        for (int r = 0; r < 4; ++r) {
          int m = mb + r;
          float v = acc[mt][nt][r] + bias[n];
          outF[(size_t)m * N + n] = resid[(size_t)m * N + n] + v;
        }
      } else if (MODE == 3) {
        float* P = outF + (size_t)blockIdx.z * M * N;
#pragma unroll
        for (int r = 0; r < 4; ++r)
          P[(size_t)(mb + r) * N + n] = acc[mt][nt][r];
      } else {
#pragma unroll
        for (int r = 0; r < 4; ++r) {
          int m = mb + r;
          float v = acc[mt][nt][r] + bias[n];
          float gl = 0.5f * v * (1.f + erff(v * 0.70710678118654752f));
          outB[(size_t)m * N + n] = f2bf(gl);
        }
      }
    }
}

// ---------------- fused causal flash attention ------------------------------
__global__ __launch_bounds__(256) void attn_fused(
    const unsigned short* __restrict__ Q, const unsigned short* __restrict__ Kg,
    const unsigned short* __restrict__ Vt, unsigned short* __restrict__ Y) {
  __shared__ __align__(16) unsigned short Ks[64 * 72];
  __shared__ __align__(16) unsigned short Vs[64 * 72];
  __shared__ __align__(16) unsigned short Ps[4][16 * 72];
  int tid = threadIdx.x;
  int wv = tid >> 6, lane = tid & 63, quad = lane >> 4, l15 = lane & 15;
  int l = blockIdx.x;
  int w = l >> 8, c = l & 255;
  int i = c & 31;
  int bh = w * 8 + (c >> 5);
  int qt;
  if (w == 0)      qt = i;
  else if (w == 1) qt = (i + 16) & 31;
  else             qt = (i < 16) ? (30 - 2 * i) : (63 - 2 * i);
  int bbx = bh / H_, hh = bh - bbx * H_;
  int q0 = qt * 64;
  size_t base = (size_t)bh * T_ * D_;
  size_t vbase = (size_t)bh * D_ * T_;
  int qrow = q0 + wv * 16 + l15;
  s16x8 qf0 = *(const s16x8*)&Q[base + (size_t)qrow * D_ + quad * 8];
  s16x8 qf1 = *(const s16x8*)&Q[base + (size_t)qrow * D_ + 32 + quad * 8];
  float lsum[4];
  fx4 oacc[4];
#pragma unroll
  for (int t = 0; t < 4; ++t) {
    lsum[t] = 0.f;
    oacc[t] = fx4{0.f, 0.f, 0.f, 0.f};
  }
  int r0s = tid >> 3;
  int c8 = (tid & 7) * 8;
  uint4 ka, kc, va, vc;
  {
    ka = *(const uint4*)&Kg[base + (size_t)r0s * D_ + c8];
    kc = *(const uint4*)&Kg[base + (size_t)(r0s + 32) * D_ + c8];
    va = *(const uint4*)&Vt[vbase + (size_t)r0s * T_ + c8];
    vc = *(const uint4*)&Vt[vbase + (size_t)(r0s + 32) * T_ + c8];
  }
  for (int kb = 0; kb <= qt; ++kb) {
    int k0 = kb * 64;
    __syncthreads();
    *(uint4*)&Ks[r0s * 72 + c8] = ka;
    *(uint4*)&Ks[(r0s + 32) * 72 + c8] = kc;
    *(uint4*)&Vs[r0s * 72 + c8] = va;
    *(uint4*)&Vs[(r0s + 32) * 72 + c8] = vc;
    __syncthreads();
    if (kb < qt) {
      int kn = k0 + 64;
      ka = *(const uint4*)&Kg[base + (size_t)(kn + r0s) * D_ + c8];
      kc = *(const uint4*)&Kg[base + (size_t)(kn + r0s + 32) * D_ + c8];
      va = *(const uint4*)&Vt[vbase + (size_t)r0s * T_ + kn + c8];
      vc = *(const uint4*)&Vt[vbase + (size_t)(r0s + 32) * T_ + kn + c8];
    }
    fx4 sc[4];
#pragma unroll
    for (int nt = 0; nt < 4; ++nt) {
      sc[nt] = fx4{0.f, 0.f, 0.f, 0.f};
      s16x8 kf0 = *(const s16x8*)&Ks[(nt * 16 + l15) * 72 + quad * 8];
      s16x8 kf1 = *(const s16x8*)&Ks[(nt * 16 + l15) * 72 + 32 + quad * 8];
      sc[nt] = __builtin_amdgcn_mfma_f32_16x16x32_bf16(qf0, kf0, sc[nt], 0, 0, 0);
      sc[nt] = __builtin_amdgcn_mfma_f32_16x16x32_bf16(qf1, kf1, sc[nt], 0, 0, 0);
    }
    bool diag = (kb == qt);
    unsigned short* pw = &Ps[wv][0];
#pragma unroll
    for (int nt = 0; nt < 4; ++nt)
#pragma unroll
      for (int r = 0; r < 4; ++r) {
        float p;
        if (diag && (k0 + nt * 16 + l15) > (q0 + wv * 16 + quad * 4 + r)) {
          p = 0.f;
        } else {
          p = __expf(sc[nt][r] * 0.125f);
        }
        lsum[r] += p;
        pw[(quad * 4 + r) * 72 + nt * 16 + l15] = f2bf_trunc(p);
      }
    s16x8 pa0 = *(const s16x8*)&pw[l15 * 72 + quad * 8];
    s16x8 pa1 = *(const s16x8*)&pw[l15 * 72 + 32 + quad * 8];
#pragma unroll
    for (int nt = 0; nt < 4; ++nt) {
      s16x8 vf0 = *(const s16x8*)&Vs[(nt * 16 + l15) * 72 + quad * 8];
      s16x8 vf1 = *(const s16x8*)&Vs[(nt * 16 + l15) * 72 + 32 + quad * 8];
      oacc[nt] = __builtin_amdgcn_mfma_f32_16x16x32_bf16(pa0, vf0, oacc[nt], 0, 0, 0);
      oacc[nt] = __builtin_amdgcn_mfma_f32_16x16x32_bf16(pa1, vf1, oacc[nt], 0, 0, 0);
    }
  }
#pragma unroll
  for (int r = 0; r < 4; ++r) {
#pragma unroll
    for (int off = 1; off < 16; off <<= 1) lsum[r] += __shfl_xor(lsum[r], off);
  }
#pragma unroll
  for (int nt = 0; nt < 4; ++nt)
#pragma unroll
    for (int r = 0; r < 4; ++r) {
      float o = oacc[nt][r] / lsum[r];
      int token = bbx * T_ + q0 + wv * 16 + quad * 4 + r;
      Y[(size_t)token * C_ + hh * D_ + nt * 16 + l15] = f2bf(o);
    }
}

// ---------------- launcher --------------------------------------------------
extern "C" void kernel_launch(void* const* d_in, const int* in_sizes, int n_in,
                              void* d_out, int out_size, void* d_ws, size_t ws_size,
                              hipStream_t stream) {
  const float* x      = (const float*)d_in[0];
  const float* ln1g   = (const float*)d_in[1];
  const float* ln1b   = (const float*)d_in[2];
  const float* Wattn  = (const float*)d_in[3];
  const float* battn  = (const float*)d_in[4];
  const float* Wcproj = (const float*)d_in[5];
  const float* bcproj = (const float*)d_in[6];
  const float* ln2g   = (const float*)d_in[7];
  const float* ln2b   = (const float*)d_in[8];
  const float* Wfc    = (const float*)d_in[9];
  const float* bfc    = (const float*)d_in[10];
  const float* Wmproj = (const float*)d_in[11];
  const float* bmproj = (const float*)d_in[12];
  float* out = (float*)d_out;
  char* ws = (char*)d_ws;

  unsigned short* WattnT  = (unsigned short*)(ws + 0);          // 2304x768 bf16
  unsigned short* WcprojT = (unsigned short*)(ws + 3538944);    // 768x768
  unsigned short* WfcT    = (unsigned short*)(ws + 4718592);    // 3072x768
  unsigned short* WmprojT = (unsigned short*)(ws + 9437184);    // 768x3072
  unsigned short* hbuf    = (unsigned short*)(ws + 14155776);   // 4096x768 bf16
  unsigned short* Qb      = (unsigned short*)(ws + 20447232);   // [24,2048,64]
  unsigned short* Kb      = (unsigned short*)(ws + 26738688);   // [24,2048,64]
  unsigned short* Vtb     = (unsigned short*)(ws + 33030144);   // [24,64,2048]
  unsigned short* Yb      = (unsigned short*)(ws + 39321600);   // 4096x768 bf16
  float*          x1      = (float*)(ws + 45613056);            // 4096x768 fp32
  unsigned short* Ab      = (unsigned short*)(ws + 58195968);   // 4096x3072 bf16
  // split-K partials overlay Qb..Yb (dead after cproj): 2 x 4096x768 fp32
  float*          Pbuf    = (float*)(ws + 20447232);

  prep<<<11008, 256, 0, stream>>>(Wattn, Wcproj, Wfc, Wmproj,
                                  WattnT, WcprojT, WfcT, WmprojT,
                                  x, ln1g, ln1b, hbuf);

  // qkv: BM=128 BN=96 BK=32 -> 768 blocks, 28KB LDS => 3/CU fully resident
  gemm_db<128, 96, 32, 0><<<dim3(24, 32), 256, 0, stream>>>(
      hbuf, WattnT, battn, nullptr, nullptr, nullptr, Qb, Kb, Vtb,
      4096, 2304, 768, 768);

  attn_fused<<<768, 256, 0, stream>>>(Qb, Kb, Vtb, Yb);

  // cproj: BM=128 BN=64 BK=64 swizzled, 384 blocks (r7 best-known config)
  gemm_db<128, 64, 64, 1><<<dim3(32, 12), 256, 0, stream>>>(
      Yb, WcprojT, bcproj, x, x1, nullptr, nullptr, nullptr, nullptr,
      4096, 768, 768, 768);

  layernorm_bf16<<<4096, 256, 0, stream>>>(x1, ln2g, ln2b, hbuf);

  gemm_db<128, 128, 32, 2><<<dim3(24, 32), 256, 0, stream>>>(
      hbuf, WfcT, bfc, nullptr, nullptr, Ab, nullptr, nullptr, nullptr,
      4096, 3072, 768, 768);

  // mproj split-K=2: 768 blocks = 3/CU resident uniform, K chunks of 1536
  gemm_db<128, 64, 64, 3><<<dim3(32, 12, 2), 256, 0, stream>>>(
      Ab, WmprojT, bmproj, nullptr, Pbuf, nullptr, nullptr, nullptr, nullptr,
      4096, 768, 3072, 1536);

  // out = x1 + P0 + P1 + bias  (786432 float4 / 256 per block = 3072 blocks)
  reduce_out<<<3072, 256, 0, stream>>>(x1, Pbuf, bmproj, out);
}